// Round 18
// baseline (408.532 us; speedup 1.0000x reference)
//
#include <hip/hip_runtime.h>
#include <math.h>

// EncoderBlock: pre-LN attention + FFN, bf16 MFMA compute, fp32 residual spine.
// B=4 T=2048 D=1024 H=16 dk=64 DFF=4096
// R3: swapped QK^T -> lane-local P; PV from P registers.
// R10: PV -> mfma 16x16x32_f16, kv-permuted V^T. R13: fast-erf GELU, 3-buf GEMM.
// R14: attn KVBLK=64. R16: 2 Q-frags/wave (LDS-read per FLOP halved).
// R17: EP_RESID/EP_GELU GEMMs compute C^T via swapped mfma(B,A) -> each lane
//      holds 4 CONSECUTIVE n values -> epilogue stores become bf16x4/float4
//      (128 scalar stores -> 32 wide stores; resid loads likewise). QKV keeps
//      unswapped order (V^T output needs column-major t).

#define D_MODEL 1024
#define D_FF    4096
#define NH      16
#define BATCH   4
#define SEQ     2048
#define DK      64
#define MTOK    (BATCH*SEQ)   // 8192
#define NBH     (BATCH*NH)    // 64

typedef __bf16 bf16;
typedef _Float16 f16;
typedef bf16  bf16x4 __attribute__((ext_vector_type(4)));
typedef bf16  bf16x8 __attribute__((ext_vector_type(8)));
typedef f16   f16x4  __attribute__((ext_vector_type(4)));
typedef f16   f16x8  __attribute__((ext_vector_type(8)));
typedef __fp16 hf16x2 __attribute__((ext_vector_type(2)));
typedef __fp16 hf16x4 __attribute__((ext_vector_type(4)));
typedef __fp16 hf16x8 __attribute__((ext_vector_type(8)));
typedef float f32x4  __attribute__((ext_vector_type(4)));

__device__ __forceinline__ void gload_lds16(const void* g, void* l) {
  __builtin_amdgcn_global_load_lds(
      (__attribute__((address_space(1))) void*)g,
      (__attribute__((address_space(3))) void*)l, 16, 0, 0);
}

#define BAR() __builtin_amdgcn_s_barrier()
#define WAIT_VM0() do { asm volatile("s_waitcnt vmcnt(0)" ::: "memory"); \
  __builtin_amdgcn_sched_barrier(0); } while (0)

// Branch-free GELU (exact-erf quality): A&S 7.1.26, |erf err| <= 1.5e-7.
__device__ __forceinline__ float gelu_fast(float x) {
  float ax = fabsf(x) * 0.70710678118654752f;
  float t  = 1.0f / (1.0f + 0.3275911f * ax);
  float p  = t * (0.254829592f + t * (-0.284496736f + t * (1.421413741f +
             t * (-1.453152027f + t * 1.061405429f))));
  float e  = __builtin_amdgcn_exp2f(ax * ax * -1.4426950408889634f);
  float er = 1.0f - p * e;                       // erf(|x|/sqrt2)
  er = __builtin_copysignf(er, x);
  return 0.5f * x * (1.0f + er);
}

// ---------------- fp32 -> bf16 cast (weights) ----------------
__global__ __launch_bounds__(256) void cast_w(const float* __restrict__ s,
                                              bf16* __restrict__ d, int n) {
  int i = (blockIdx.x * 256 + threadIdx.x) * 4;
  if (i >= n) return;
  float4 v = *(const float4*)(s + i);
  bf16x4 o;
  o[0] = (bf16)v.x; o[1] = (bf16)v.y; o[2] = (bf16)v.z; o[3] = (bf16)v.w;
  *(bf16x4*)(d + i) = o;
}

// ---------------- LayerNorm (fp32 in, bf16 out) ----------------
__global__ __launch_bounds__(256) void ln_kernel(const float* __restrict__ x,
                                                 const float* __restrict__ g,
                                                 const float* __restrict__ b,
                                                 bf16* __restrict__ out) {
  int row = blockIdx.x;
  int tid = threadIdx.x;
  const float* xr = x + (size_t)row * D_MODEL;
  float4 v = *(const float4*)(xr + tid * 4);
  float s  = v.x + v.y + v.z + v.w;
  float sq = v.x*v.x + v.y*v.y + v.z*v.z + v.w*v.w;
  #pragma unroll
  for (int off = 1; off < 64; off <<= 1) {
    s  += __shfl_xor(s,  off, 64);
    sq += __shfl_xor(sq, off, 64);
  }
  __shared__ float ls[4], lq[4];
  int wid = tid >> 6, lane = tid & 63;
  if (lane == 0) { ls[wid] = s; lq[wid] = sq; }
  __syncthreads();
  s  = ls[0] + ls[1] + ls[2] + ls[3];
  sq = lq[0] + lq[1] + lq[2] + lq[3];
  float mu   = s * (1.0f / D_MODEL);
  float var  = sq * (1.0f / D_MODEL) - mu * mu;
  float rstd = rsqrtf(var + 1e-5f);
  float4 gv = *(const float4*)(g + tid * 4);
  float4 bv = *(const float4*)(b + tid * 4);
  bf16x4 o;
  o[0] = (bf16)((v.x - mu) * rstd * gv.x + bv.x);
  o[1] = (bf16)((v.y - mu) * rstd * gv.y + bv.y);
  o[2] = (bf16)((v.z - mu) * rstd * gv.z + bv.z);
  o[3] = (bf16)((v.w - mu) * rstd * gv.w + bv.w);
  *(bf16x4*)(out + (size_t)row * D_MODEL + tid * 4) = o;
}

// ---------------- GEMM: C[M,N] = A[M,K] @ W[N,K]^T (+bias, epilogue) --------
enum { EP_QKV = 0, EP_RESID = 1, EP_GELU = 2 };

#define QSCALE 0.18033688011112042f  // (1/8) * log2(e)

// CFG 0: BM=256 BN=256 BK=32, wave tile 128x64
// CFG 1: BM=128 BN=256 BK=64, wave tile 64x64
// EP != EP_QKV: mfma operands swapped -> acc holds C^T fragments
// (lane: row gm = f*16+l15 fixed, cols gn = fc*16 + l4*4 + 0..3 consecutive).
template <int EP, int CFG>
__global__ __launch_bounds__(512) void gemm8p(
    const bf16* __restrict__ A, const bf16* __restrict__ W,
    const float* __restrict__ bias,
    const float* __restrict__ resid,
    float* __restrict__ out_f32,
    bf16* __restrict__ out_bf,
    int M, int N, int K) {
  constexpr int BM  = CFG ? 128 : 256;
  constexpr int BK  = CFG ? 64 : 32;
  constexpr int WM  = CFG ? 64 : 128;     // wave-tile rows
  constexpr int FRN = WM / 16;            // frag rows per wave
  constexpr int KKN = BK / 32;            // k-steps per K-tile
  constexpr int RB  = BK * 2;             // LDS row bytes
  constexpr int GR  = RB / 16;            // 16B granules per row
  constexpr int RSH = CFG ? 7 : 6;        // log2(RB)
  constexpr int AB  = 16384;              // A region bytes
  constexpr int TB  = AB + 256 * BK * 2;  // tile bytes
  constexpr int L   = TB / 8192;          // gloads/thread/K-tile (4 or 6)

  __shared__ char lds[3 * TB];

  int tiles_n = N >> 8;
  int nwg = (M / BM) * tiles_n;
  int bid = blockIdx.x;
  int swz = (bid & 7) * (nwg >> 3) + (bid >> 3);
  int bm = swz / tiles_n, bn = swz % tiles_n;
  int m0 = bm * BM, n0 = bn << 8;
  int tid = threadIdx.x, wid = tid >> 6, lane = tid & 63;
  int wm = wid >> 2, wn = wid & 3;        // 2M x 4N
  int l15 = lane & 15, l4 = lane >> 4;

  f32x4 acc[FRN][4];
  #pragma unroll
  for (int i = 0; i < FRN; i++)
    #pragma unroll
    for (int j = 0; j < 4; j++)
      #pragma unroll
      for (int e = 0; e < 4; e++) acc[i][j][e] = 0.f;

  // stage all L chunks of K-tile kt into ring buffer nb
  auto STAGE = [&](int kt, int nb) {
    char* buf = lds + nb * TB;
    #pragma unroll
    for (int l = 0; l < L; ++l) {
      bool isA = l < 2;
      int o = (isA ? l : l - 2) * 8192 + tid * 16;
      int row = o >> RSH;
      int g = (o >> 4) & (GR - 1);
      int gs = g ^ (CFG ? (row & 7) : ((row >> 1) & 3));
      const bf16* src = (isA ? A + (size_t)(m0 + row) * K
                             : W + (size_t)(n0 + row) * K) + kt * BK + gs * 8;
      gload_lds16(src, buf + (isA ? 0 : AB) + o);
    }
  };

  int nt = K / BK;
  STAGE(0, 0);
  STAGE(1, 1);
  if constexpr (CFG) { asm volatile("s_waitcnt vmcnt(6)" ::: "memory"); }
  else               { asm volatile("s_waitcnt vmcnt(4)" ::: "memory"); }
  __builtin_amdgcn_sched_barrier(0);
  BAR();

  for (int t = 0; t < nt; ++t) {
    int cb = t % 3, nb = cb >= 1 ? cb - 1 : 2;  // (t+2)%3
    const char* bc = lds + cb * TB;

    if (t + 2 < nt) STAGE(t + 2, nb);   // issue early (vmem pipe)

    bf16x8 af[FRN][KKN], bfr[4][KKN];
    #pragma unroll
    for (int f = 0; f < FRN; ++f)
      #pragma unroll
      for (int kk = 0; kk < KKN; ++kk) {
        int row = wm * WM + f * 16 + l15;
        int g = (kk * 4 + l4) ^ (CFG ? (row & 7) : ((row >> 1) & 3));
        af[f][kk] = *(const bf16x8*)(bc + row * RB + g * 16);
      }
    #pragma unroll
    for (int fc = 0; fc < 4; ++fc)
      #pragma unroll
      for (int kk = 0; kk < KKN; ++kk) {
        int row = wn * 64 + fc * 16 + l15;
        int g = (kk * 4 + l4) ^ (CFG ? (row & 7) : ((row >> 1) & 3));
        bfr[fc][kk] = *(const bf16x8*)(bc + AB + row * RB + g * 16);
      }

    __builtin_amdgcn_s_setprio(1);
    #pragma unroll
    for (int f = 0; f < FRN; ++f)
      #pragma unroll
      for (int fc = 0; fc < 4; ++fc)
        #pragma unroll
        for (int kk = 0; kk < KKN; ++kk) {
          if (EP == EP_QKV)
            acc[f][fc] = __builtin_amdgcn_mfma_f32_16x16x32_bf16(af[f][kk], bfr[fc][kk],
                                                                 acc[f][fc], 0, 0, 0);
          else  // swapped: acc = C^T fragment
            acc[f][fc] = __builtin_amdgcn_mfma_f32_16x16x32_bf16(bfr[fc][kk], af[f][kk],
                                                                 acc[f][fc], 0, 0, 0);
        }
    __builtin_amdgcn_s_setprio(0);

    if (t + 2 < nt) {
      if constexpr (CFG) { asm volatile("s_waitcnt vmcnt(6)" ::: "memory"); }
      else               { asm volatile("s_waitcnt vmcnt(4)" ::: "memory"); }
      __builtin_amdgcn_sched_barrier(0);
    } else if (t + 1 < nt) {
      WAIT_VM0();
    }
    BAR();
  }

  // ----- epilogue -----
  if (EP == EP_QKV) {
    #pragma unroll
    for (int i = 0; i < FRN; i++)
      #pragma unroll
      for (int j = 0; j < 4; j++) {
        int gm0 = m0 + wm * WM + i * 16 + (l4 << 2);
        int gn  = n0 + wn * 64 + j * 16 + l15;
        int which = gn >> 10;
        int nn = gn & 1023, head = nn >> 6, d = nn & 63;
        int bb = gm0 >> 11, t = gm0 & 2047;
        float bv = bias[gn];
        if (which == 2) {
          // V^T with kv-permuted storage within each 32-token block:
          // pos(t) = (t&~31) + ((t>>2)&3)*8 + ((t>>4)&1)*4 + (t&3)
          int sbase = (t & ~31) + ((t >> 2) & 3) * 8 + ((t >> 4) & 1) * 4;
          f16x4 pk;
          #pragma unroll
          for (int jj = 0; jj < 4; jj++) pk[jj] = (f16)(acc[i][j][jj] + bv);
          *(f16x4*)((f16*)out_bf + (size_t)2 * NBH * SEQ * DK +
                    ((size_t)(bb * NH + head) * DK + d) * SEQ + sbase) = pk;
        } else {
          float scale = (which == 0) ? QSCALE : 1.0f;
          #pragma unroll
          for (int jj = 0; jj < 4; jj++) {
            float cv = (acc[i][j][jj] + bv) * scale;
            size_t idx = (size_t)which * (NBH * SEQ * DK) +
                         ((size_t)(bb * NH + head) * SEQ + (t + jj)) * DK + d;
            out_bf[idx] = (bf16)cv;
          }
        }
      }
  } else {
    // swapped layout: lane holds C[gm][gn..gn+3]
    #pragma unroll
    for (int i = 0; i < FRN; i++) {
      int gm = m0 + wm * WM + i * 16 + l15;
      #pragma unroll
      for (int j = 0; j < 4; j++) {
        int gn = n0 + wn * 64 + j * 16 + (l4 << 2);
        float4 bv4 = *(const float4*)(bias + gn);
        size_t idx = (size_t)gm * N + gn;
        if (EP == EP_RESID) {
          float4 rv = *(const float4*)(resid + idx);
          float4 ov;
          ov.x = rv.x + acc[i][j][0] + bv4.x;
          ov.y = rv.y + acc[i][j][1] + bv4.y;
          ov.z = rv.z + acc[i][j][2] + bv4.z;
          ov.w = rv.w + acc[i][j][3] + bv4.w;
          *(float4*)(out_f32 + idx) = ov;
        } else {  // EP_GELU
          bf16x4 pk;
          pk[0] = (bf16)gelu_fast(acc[i][j][0] + bv4.x);
          pk[1] = (bf16)gelu_fast(acc[i][j][1] + bv4.y);
          pk[2] = (bf16)gelu_fast(acc[i][j][2] + bv4.z);
          pk[3] = (bf16)gelu_fast(acc[i][j][3] + bv4.w);
          *(bf16x4*)(out_bf + idx) = pk;
        }
      }
    }
  }
}

// ---------------- Flash attention (R16: 2 Q-frags/wave, 32 q-rows) ---------
// grid: (T/256)*BH = 512, 512 thr = 8 waves x 32 q-rows (Q-tile 256).
// KVBLK=64. K,V LDS double-buffered (32KB). K/V fragments read ONCE per wave
// per tile, reused for both Q-fragments (halves LDS-read per FLOP).
__global__ __launch_bounds__(512) void attn_kernel(
    const bf16* __restrict__ q, const bf16* __restrict__ k,
    const f16* __restrict__ vt, bf16* __restrict__ o) {
  __shared__ bf16 kt_lds[2][64 * 64];   // [buf][kv][dk], 128B rows
  __shared__ f16  vt_lds[2][64 * 64];   // [buf][d][kv-permuted], 128B rows
  int bid = blockIdx.x;
  int swzb = (bid & 7) * 64 + (bid >> 3);    // XCD-chunk: same-bh co-located
  int bh = swzb >> 3;
  int qt = swzb & 7;
  int t0 = qt << 8;                          // 256-row Q-tile
  int tid = threadIdx.x, wid = tid >> 6, lane = tid & 63;
  int l15 = lane & 15, l4 = lane >> 4;

  // ---- hoisted per-lane LDS read bases ----
  int kb0 = l15 * 128 + ((l4 ^ (l15 & 7)) << 4);
  int kb1 = l15 * 128 + (((4 + l4) ^ (l15 & 7)) << 4);
  int vb32[2];
  #pragma unroll
  for (int n = 0; n < 2; n++)
    vb32[n] = l15 * 128 + (((n * 4 + l4) ^ (l15 & 7)) << 4);

  // Q: two fragments, rows t0 + wid*32 + qr*16 + l15
  bf16x8 qf[2][2];
  #pragma unroll
  for (int qr = 0; qr < 2; qr++) {
    const bf16* qbase = q + ((size_t)bh * SEQ + t0 + wid * 32 + qr * 16 + l15) * DK;
    qf[qr][0] = *(const bf16x8*)(qbase + (l4 << 3));
    qf[qr][1] = *(const bf16x8*)(qbase + 32 + (l4 << 3));
  }

  f16x8 vones8;
  #pragma unroll
  for (int e = 0; e < 8; e++) vones8[e] = (f16)1.f;
  float m_run[2] = {-1e30f, -1e30f};
  f32x4 acc_o[2][4];
  f32x4 acc_l[2];
  #pragma unroll
  for (int qr = 0; qr < 2; qr++) {
    #pragma unroll
    for (int nd = 0; nd < 4; nd++)
      #pragma unroll
      for (int e = 0; e < 4; e++) acc_o[qr][nd][e] = 0.f;
    #pragma unroll
    for (int e = 0; e < 4; e++) acc_l[qr][e] = 0.f;
  }

  // staging sources: 512 thr x 16B = 8KB each for K and V per 64-kv tile
  int oK = tid * 16;
  int rowk = oK >> 7, gk = (oK >> 4) & 7;               // K: 128B rows
  const bf16* gKsrc = k + ((size_t)bh * SEQ + rowk) * DK + ((gk ^ (rowk & 7)) << 3);
  int dV = oK >> 7, gd = (oK >> 4) & 7;                 // V: 128B rows (64 kv)
  const f16* gVsrc = vt + ((size_t)bh * DK + dV) * SEQ + ((gd ^ (dV & 7)) << 3);

  auto stage = [&](int buf, int t) {
    int kv0 = t * 64;
    gload_lds16(gKsrc + (size_t)kv0 * DK, (char*)&kt_lds[buf][0] + tid * 16);
    gload_lds16(gVsrc + kv0, (char*)&vt_lds[buf][0] + tid * 16);
  };

  stage(0, 0);
  WAIT_VM0();
  BAR();

  for (int t = 0; t < SEQ / 64; ++t) {
    int cur = t & 1;
    if (t < SEQ / 64 - 1) stage(cur ^ 1, t + 1);
    const char* kbase = (const char*)&kt_lds[cur][0];
    const char* vbase = (const char*)&vt_lds[cur][0];

    // S = K Q^T (swapped), K-frags read once, used for both Q-frags
    f32x4 accs[2][4];
    #pragma unroll
    for (int qr = 0; qr < 2; qr++)
      #pragma unroll
      for (int n = 0; n < 4; n++)
        #pragma unroll
        for (int e = 0; e < 4; e++) accs[qr][n][e] = 0.f;
    __builtin_amdgcn_s_setprio(1);
    #pragma unroll
    for (int n = 0; n < 4; n++) {
      bf16x8 kf0 = *(const bf16x8*)(kbase + kb0 + n * 2048);
      bf16x8 kf1 = *(const bf16x8*)(kbase + kb1 + n * 2048);
      #pragma unroll
      for (int qr = 0; qr < 2; qr++) {
        accs[qr][n] = __builtin_amdgcn_mfma_f32_16x16x32_bf16(kf0, qf[qr][0], accs[qr][n], 0, 0, 0);
        accs[qr][n] = __builtin_amdgcn_mfma_f32_16x16x32_bf16(kf1, qf[qr][1], accs[qr][n], 0, 0, 0);
      }
    }
    __builtin_amdgcn_s_setprio(0);

    // online softmax (log2 domain) per Q-frag, lane-local row q=l15
    f16x8 pa32[2][2];
    #pragma unroll
    for (int qr = 0; qr < 2; qr++) {
      float mloc = -1e30f;
      #pragma unroll
      for (int n = 0; n < 4; n++) {
        float a0 = fmaxf(accs[qr][n][0], accs[qr][n][1]);
        float a1 = fmaxf(accs[qr][n][2], accs[qr][n][3]);
        mloc = fmaxf(mloc, fmaxf(a0, a1));
      }
      float mt = fmaxf(mloc, __shfl_xor(mloc, 16, 64));
      mt = fmaxf(mt, __shfl_xor(mt, 32, 64));
      if (__any(mt > m_run[qr] + 8.0f)) {
        float mn = fmaxf(m_run[qr], mt);
        float sc = __builtin_amdgcn_exp2f(m_run[qr] - mn);
        m_run[qr] = mn;
        float scr0 = __shfl(sc, l4 * 20 + 0, 64);
        float scr1 = __shfl(sc, l4 * 20 + 1, 64);
        float scr2 = __shfl(sc, l4 * 20 + 2, 64);
        float scr3 = __shfl(sc, l4 * 20 + 3, 64);
        #pragma unroll
        for (int nd = 0; nd < 4; nd++) {
          acc_o[qr][nd][0] *= scr0; acc_o[qr][nd][1] *= scr1;
          acc_o[qr][nd][2] *= scr2; acc_o[qr][nd][3] *= scr3;
        }
        acc_l[qr][0] *= scr0; acc_l[qr][1] *= scr1;
        acc_l[qr][2] *= scr2; acc_l[qr][3] *= scr3;
      }
      #pragma unroll
      for (int n = 0; n < 2; n++) {
        float e0 = __builtin_amdgcn_exp2f(accs[qr][2*n][0] - m_run[qr]);
        float e1 = __builtin_amdgcn_exp2f(accs[qr][2*n][1] - m_run[qr]);
        float e2 = __builtin_amdgcn_exp2f(accs[qr][2*n][2] - m_run[qr]);
        float e3 = __builtin_amdgcn_exp2f(accs[qr][2*n][3] - m_run[qr]);
        float e4 = __builtin_amdgcn_exp2f(accs[qr][2*n+1][0] - m_run[qr]);
        float e5 = __builtin_amdgcn_exp2f(accs[qr][2*n+1][1] - m_run[qr]);
        float e6 = __builtin_amdgcn_exp2f(accs[qr][2*n+1][2] - m_run[qr]);
        float e7 = __builtin_amdgcn_exp2f(accs[qr][2*n+1][3] - m_run[qr]);
        hf16x2 p01 = __builtin_amdgcn_cvt_pkrtz(e0, e1);
        hf16x2 p23 = __builtin_amdgcn_cvt_pkrtz(e2, e3);
        hf16x2 p45 = __builtin_amdgcn_cvt_pkrtz(e4, e5);
        hf16x2 p67 = __builtin_amdgcn_cvt_pkrtz(e6, e7);
        hf16x4 lo = __builtin_shufflevector(p01, p23, 0, 1, 2, 3);
        hf16x4 hi = __builtin_shufflevector(p45, p67, 0, 1, 2, 3);
        hf16x8 cmb = __builtin_shufflevector(lo, hi, 0, 1, 2, 3, 4, 5, 6, 7);
        pa32[qr][n] = __builtin_bit_cast(f16x8, cmb);
      }
    }

    // O += P @ V (K=32 f16): V-frags read once, used for both Q-frags
    __builtin_amdgcn_s_setprio(1);
    #pragma unroll
    for (int n = 0; n < 2; n++) {
      #pragma unroll
      for (int nd = 0; nd < 4; nd++) {
        f16x8 vf = *(const f16x8*)(vbase + vb32[n] + nd * 2048);
        #pragma unroll
        for (int qr = 0; qr < 2; qr++)
          acc_o[qr][nd] = __builtin_amdgcn_mfma_f32_16x16x32_f16(pa32[qr][n], vf, acc_o[qr][nd], 0, 0, 0);
      }
      #pragma unroll
      for (int qr = 0; qr < 2; qr++)
        acc_l[qr] = __builtin_amdgcn_mfma_f32_16x16x32_f16(pa32[qr][n], vones8, acc_l[qr], 0, 0, 0);
    }
    __builtin_amdgcn_s_setprio(0);

    if (t < SEQ / 64 - 1) { WAIT_VM0(); }
    BAR();
  }

  int bb = bh >> 4, hh = bh & 15;
  #pragma unroll
  for (int qr = 0; qr < 2; qr++) {
    float rl0 = 1.0f / acc_l[qr][0], rl1 = 1.0f / acc_l[qr][1];
    float rl2 = 1.0f / acc_l[qr][2], rl3 = 1.0f / acc_l[qr][3];
    int rowb = t0 + wid * 32 + qr * 16 + l4 * 4;
    #pragma unroll
    for (int nd = 0; nd < 4; nd++) {
      int d = nd * 16 + l15;
      o[((size_t)bb * SEQ + rowb + 0) * D_MODEL + hh * DK + d] = (bf16)(acc_o[qr][nd][0] * rl0);
      o[((size_t)bb * SEQ + rowb + 1) * D_MODEL + hh * DK + d] = (bf16)(acc_o[qr][nd][1] * rl1);
      o[((size_t)bb * SEQ + rowb + 2) * D_MODEL + hh * DK + d] = (bf16)(acc_o[qr][nd][2] * rl2);
      o[((size_t)bb * SEQ + rowb + 3) * D_MODEL + hh * DK + d] = (bf16)(acc_o[qr][nd][3] * rl3);
    }
  }
}

// ---------------- launch ----------------
extern "C" void kernel_launch(void* const* d_in, const int* in_sizes, int n_in,
                              void* d_out, int out_size, void* d_ws, size_t ws_size,
                              hipStream_t stream) {
  const float* x    = (const float*)d_in[0];
  const float* ln1g = (const float*)d_in[1];
  const float* ln1b = (const float*)d_in[2];
  const float* wq   = (const float*)d_in[3];
  const float* bq   = (const float*)d_in[4];
  const float* wk   = (const float*)d_in[5];
  const float* bk   = (const float*)d_in[6];
  const float* wv   = (const float*)d_in[7];
  const float* bv   = (const float*)d_in[8];
  const float* wo   = (const float*)d_in[9];
  const float* bo   = (const float*)d_in[10];
  const float* ln2g = (const float*)d_in[11];
  const float* ln2b = (const float*)d_in[12];
  const float* w1   = (const float*)d_in[13];
  const float* b1   = (const float*)d_in[14];
  const float* w2   = (const float*)d_in[15];
  const float* b2   = (const float*)d_in[16];
  float* out = (float*)d_out;

  char* ws = (char*)d_ws;
  bf16* wqkv_b = (bf16*)(ws);                          // 6MB
  bf16* wo_b   = (bf16*)(ws + ((size_t)6  << 20));     // 2MB
  bf16* w1_b   = (bf16*)(ws + ((size_t)8  << 20));     // 8MB
  bf16* w2_b   = (bf16*)(ws + ((size_t)16 << 20));     // 8MB
  bf16* h_b    = (bf16*)(ws + ((size_t)24 << 20));     // 16MB
  bf16* qkv_b  = (bf16*)(ws + ((size_t)40 << 20));     // 48MB q|k|vT(f16)
  bf16* o_b    = (bf16*)(ws + ((size_t)88 << 20));     // 16MB
  bf16* ffn1_b = (bf16*)(ws + ((size_t)40 << 20));     // 64MB (over dead q,k,v,o)
  float* bqkv  = (float*)(ws + ((size_t)104 << 20));   // 12KB

  cast_w<<<1024, 256, 0, stream>>>(wq, wqkv_b, 1 << 20);
  cast_w<<<1024, 256, 0, stream>>>(wk, wqkv_b + (1 << 20), 1 << 20);
  cast_w<<<1024, 256, 0, stream>>>(wv, wqkv_b + (2 << 20), 1 << 20);
  cast_w<<<1024, 256, 0, stream>>>(wo, wo_b, 1 << 20);
  cast_w<<<4096, 256, 0, stream>>>(w1, w1_b, 1 << 22);
  cast_w<<<4096, 256, 0, stream>>>(w2, w2_b, 1 << 22);
  (void)hipMemcpyAsync(bqkv,        bq, 4096, hipMemcpyDeviceToDevice, stream);
  (void)hipMemcpyAsync(bqkv + 1024, bk, 4096, hipMemcpyDeviceToDevice, stream);
  (void)hipMemcpyAsync(bqkv + 2048, bv, 4096, hipMemcpyDeviceToDevice, stream);

  ln_kernel<<<MTOK, 256, 0, stream>>>(x, ln1g, ln1b, h_b);
  gemm8p<EP_QKV, 1><<<768, 512, 0, stream>>>(h_b, wqkv_b, bqkv, nullptr, nullptr,
                                             qkv_b, MTOK, 3072, 1024);
  attn_kernel<<<512, 512, 0, stream>>>(qkv_b, qkv_b + (size_t)NBH * SEQ * DK,
                                       (const f16*)(qkv_b + (size_t)2 * NBH * SEQ * DK),
                                       o_b);
  gemm8p<EP_RESID, 1><<<256, 512, 0, stream>>>(o_b, wo_b, bo, x, out, nullptr,
                                               MTOK, 1024, 1024);
  ln_kernel<<<MTOK, 256, 0, stream>>>(out, ln2g, ln2b, h_b);
  gemm8p<EP_GELU, 0><<<512, 512, 0, stream>>>(h_b, w1_b, b1, nullptr, nullptr,
                                              ffn1_b, MTOK, 4096, 1024);
  gemm8p<EP_RESID, 1><<<256, 512, 0, stream>>>(ffn1_b, w2_b, b2, out, out, nullptr,
                                               MTOK, 1024, 4096);
}

// Round 19
// 392.816 us; speedup vs baseline: 1.0400x; 1.0400x over previous
//
#include <hip/hip_runtime.h>
#include <math.h>

// EncoderBlock: pre-LN attention + FFN, bf16 MFMA compute, fp32 residual spine.
// B=4 T=2048 D=1024 H=16 dk=64 DFF=4096
// R3: swapped QK^T -> lane-local P. R10: PV 16x16x32_f16, kv-permuted V^T.
// R13: fast-erf GELU. R16: attn 2 Q-frags/wave. R17: C^T epilogue (wide stores).
// R18: QKV+FFN1 -> m201-style 8-phase 256^2 GEMM (BK=64, 8 waves 2Mx4N, wave
//      128x64, LDS 128KB dbuf): 4 phases/K-tile {ds-read || stage 1 half-tile,
//      BAR, lgkmcnt(0), setprio, 16 MFMA, BAR}, vmcnt(4) once per K-tile.
//      A-frags reg-cached across phases. O/FFN2 (N=1024) stay CFG1 gemm8p.

#define D_MODEL 1024
#define D_FF    4096
#define NH      16
#define BATCH   4
#define SEQ     2048
#define DK      64
#define MTOK    (BATCH*SEQ)   // 8192
#define NBH     (BATCH*NH)    // 64

typedef __bf16 bf16;
typedef _Float16 f16;
typedef bf16  bf16x4 __attribute__((ext_vector_type(4)));
typedef bf16  bf16x8 __attribute__((ext_vector_type(8)));
typedef f16   f16x4  __attribute__((ext_vector_type(4)));
typedef f16   f16x8  __attribute__((ext_vector_type(8)));
typedef __fp16 hf16x2 __attribute__((ext_vector_type(2)));
typedef __fp16 hf16x4 __attribute__((ext_vector_type(4)));
typedef __fp16 hf16x8 __attribute__((ext_vector_type(8)));
typedef float f32x4  __attribute__((ext_vector_type(4)));

__device__ __forceinline__ void gload_lds16(const void* g, void* l) {
  __builtin_amdgcn_global_load_lds(
      (__attribute__((address_space(1))) void*)g,
      (__attribute__((address_space(3))) void*)l, 16, 0, 0);
}

#define BAR() __builtin_amdgcn_s_barrier()
#define LGKM0() do { asm volatile("s_waitcnt lgkmcnt(0)" ::: "memory"); \
  __builtin_amdgcn_sched_barrier(0); } while (0)
#define WAIT_VM0() do { asm volatile("s_waitcnt vmcnt(0)" ::: "memory"); \
  __builtin_amdgcn_sched_barrier(0); } while (0)
#define WAIT_VM4() do { asm volatile("s_waitcnt vmcnt(4)" ::: "memory"); \
  __builtin_amdgcn_sched_barrier(0); } while (0)

// Branch-free GELU (exact-erf quality): A&S 7.1.26, |erf err| <= 1.5e-7.
__device__ __forceinline__ float gelu_fast(float x) {
  float ax = fabsf(x) * 0.70710678118654752f;
  float t  = 1.0f / (1.0f + 0.3275911f * ax);
  float p  = t * (0.254829592f + t * (-0.284496736f + t * (1.421413741f +
             t * (-1.453152027f + t * 1.061405429f))));
  float e  = __builtin_amdgcn_exp2f(ax * ax * -1.4426950408889634f);
  float er = 1.0f - p * e;
  er = __builtin_copysignf(er, x);
  return 0.5f * x * (1.0f + er);
}

// ---------------- fp32 -> bf16 cast (weights) ----------------
__global__ __launch_bounds__(256) void cast_w(const float* __restrict__ s,
                                              bf16* __restrict__ d, int n) {
  int i = (blockIdx.x * 256 + threadIdx.x) * 4;
  if (i >= n) return;
  float4 v = *(const float4*)(s + i);
  bf16x4 o;
  o[0] = (bf16)v.x; o[1] = (bf16)v.y; o[2] = (bf16)v.z; o[3] = (bf16)v.w;
  *(bf16x4*)(d + i) = o;
}

// ---------------- LayerNorm (fp32 in, bf16 out) ----------------
__global__ __launch_bounds__(256) void ln_kernel(const float* __restrict__ x,
                                                 const float* __restrict__ g,
                                                 const float* __restrict__ b,
                                                 bf16* __restrict__ out) {
  int row = blockIdx.x;
  int tid = threadIdx.x;
  const float* xr = x + (size_t)row * D_MODEL;
  float4 v = *(const float4*)(xr + tid * 4);
  float s  = v.x + v.y + v.z + v.w;
  float sq = v.x*v.x + v.y*v.y + v.z*v.z + v.w*v.w;
  #pragma unroll
  for (int off = 1; off < 64; off <<= 1) {
    s  += __shfl_xor(s,  off, 64);
    sq += __shfl_xor(sq, off, 64);
  }
  __shared__ float ls[4], lq[4];
  int wid = tid >> 6, lane = tid & 63;
  if (lane == 0) { ls[wid] = s; lq[wid] = sq; }
  __syncthreads();
  s  = ls[0] + ls[1] + ls[2] + ls[3];
  sq = lq[0] + lq[1] + lq[2] + lq[3];
  float mu   = s * (1.0f / D_MODEL);
  float var  = sq * (1.0f / D_MODEL) - mu * mu;
  float rstd = rsqrtf(var + 1e-5f);
  float4 gv = *(const float4*)(g + tid * 4);
  float4 bv = *(const float4*)(b + tid * 4);
  bf16x4 o;
  o[0] = (bf16)((v.x - mu) * rstd * gv.x + bv.x);
  o[1] = (bf16)((v.y - mu) * rstd * gv.y + bv.y);
  o[2] = (bf16)((v.z - mu) * rstd * gv.z + bv.z);
  o[3] = (bf16)((v.w - mu) * rstd * gv.w + bv.w);
  *(bf16x4*)(out + (size_t)row * D_MODEL + tid * 4) = o;
}

enum { EP_QKV = 0, EP_RESID = 1, EP_GELU = 2 };
#define QSCALE 0.18033688011112042f  // (1/8) * log2(e)

// ---------- 8-phase 256x256 GEMM (m201 port), BK=64, used for QKV/FFN1 -----
// LDS per buffer 64KB: A rows 0-255 (128B rows) @0, B rows 0-255 @32768.
// Granule swizzle g ^= row&7 both sides. Half-tiles h: 0=A-lo 1=A-hi 2=B-lo
// 3=B-hi (16KB each = 2 gload_lds/thread). Per K-tile 4 phases (one n-frag
// each); stage: P1->B-lo(t+1) P2->B-hi(t+1) P3->A-lo(t+2) P4->A-hi(t+2);
// vmcnt(4) at P4. A-frags reg-cached across phases.
template <int EP>
__global__ __launch_bounds__(512, 2) void gemm256(
    const bf16* __restrict__ A, const bf16* __restrict__ W,
    const float* __restrict__ bias,
    bf16* __restrict__ out_bf,
    int M, int N, int K) {
  __shared__ char lds[131072];
  int tiles_n = N >> 8;
  int nwg = (M >> 8) * tiles_n;
  int bid = blockIdx.x;
  int swz = (bid & 7) * (nwg >> 3) + (bid >> 3);
  int bm = swz / tiles_n, bn = swz % tiles_n;
  int m0 = bm << 8, n0 = bn << 8;
  int tid = threadIdx.x, wid = tid >> 6, lane = tid & 63;
  int wm = wid >> 2, wn = wid & 3;        // 2M x 4N, wave tile 128x64
  int l15 = lane & 15, l4 = lane >> 4;

  f32x4 acc[8][4];
  #pragma unroll
  for (int f = 0; f < 8; f++)
    #pragma unroll
    for (int n = 0; n < 4; n++)
      #pragma unroll
      for (int e = 0; e < 4; e++) acc[f][n][e] = 0.f;

  // stage half-tile h of K-tile kt into buffer bsel
  auto STAGEH = [&](int h, int kt, int bsel) {
    char* buf = lds + bsel * 65536;
    #pragma unroll
    for (int l = 0; l < 2; ++l) {
      int o = h * 16384 + l * 8192 + tid * 16;
      int row = (o >> 7) & 255;
      int g = (o >> 4) & 7;
      int gs = g ^ (row & 7);
      const bf16* src = (h < 2 ? A + (size_t)(m0 + row) * K
                               : W + (size_t)(n0 + row) * K) + kt * 64 + gs * 8;
      gload_lds16(src, buf + o);
    }
  };
  // B-fragment read (n-frag idx, kk) from buffer base
  auto RDB = [&](const char* bc, int n, int kk) -> bf16x8 {
    int row = wn * 64 + n * 16 + l15;
    return *(const bf16x8*)(bc + 32768 + row * 128 + (((kk << 2) + l4) ^ (row & 7)) * 16);
  };

  int nt = K >> 6;
  // prologue: tile0 fully + tile1 A halves
  STAGEH(0, 0, 0); STAGEH(1, 0, 0); STAGEH(2, 0, 0); STAGEH(3, 0, 0);
  STAGEH(0, 1, 1); STAGEH(1, 1, 1);
  WAIT_VM4();
  BAR();

  for (int t = 0; t < nt; ++t) {
    const char* bc = lds + (t & 1) * 65536;
    bf16x8 af[8][2];

    // ---- P1: read all A-frags + B n=0; stage B-lo(t+1) ----
    #pragma unroll
    for (int f = 0; f < 8; ++f)
      #pragma unroll
      for (int kk = 0; kk < 2; ++kk) {
        int row = wm * 128 + f * 16 + l15;
        af[f][kk] = *(const bf16x8*)(bc + row * 128 + (((kk << 2) + l4) ^ (row & 7)) * 16);
      }
    bf16x8 b0[2];
    b0[0] = RDB(bc, 0, 0); b0[1] = RDB(bc, 0, 1);
    if (t + 1 < nt) STAGEH(2, t + 1, (t + 1) & 1);
    BAR(); LGKM0();
    __builtin_amdgcn_s_setprio(1);
    #pragma unroll
    for (int f = 0; f < 8; ++f)
      #pragma unroll
      for (int kk = 0; kk < 2; ++kk) {
        if (EP == EP_QKV)
          acc[f][0] = __builtin_amdgcn_mfma_f32_16x16x32_bf16(af[f][kk], b0[kk], acc[f][0], 0, 0, 0);
        else
          acc[f][0] = __builtin_amdgcn_mfma_f32_16x16x32_bf16(b0[kk], af[f][kk], acc[f][0], 0, 0, 0);
      }
    __builtin_amdgcn_s_setprio(0);
    BAR();

    // ---- P2: read B n=1; stage B-hi(t+1) ----
    bf16x8 b1[2];
    b1[0] = RDB(bc, 1, 0); b1[1] = RDB(bc, 1, 1);
    if (t + 1 < nt) STAGEH(3, t + 1, (t + 1) & 1);
    BAR(); LGKM0();
    __builtin_amdgcn_s_setprio(1);
    #pragma unroll
    for (int f = 0; f < 8; ++f)
      #pragma unroll
      for (int kk = 0; kk < 2; ++kk) {
        if (EP == EP_QKV)
          acc[f][1] = __builtin_amdgcn_mfma_f32_16x16x32_bf16(af[f][kk], b1[kk], acc[f][1], 0, 0, 0);
        else
          acc[f][1] = __builtin_amdgcn_mfma_f32_16x16x32_bf16(b1[kk], af[f][kk], acc[f][1], 0, 0, 0);
      }
    __builtin_amdgcn_s_setprio(0);
    BAR();

    // ---- P3: read B n=2; stage A-lo(t+2) ----
    bf16x8 b2[2];
    b2[0] = RDB(bc, 2, 0); b2[1] = RDB(bc, 2, 1);
    if (t + 2 < nt) STAGEH(0, t + 2, t & 1);
    BAR(); LGKM0();
    __builtin_amdgcn_s_setprio(1);
    #pragma unroll
    for (int f = 0; f < 8; ++f)
      #pragma unroll
      for (int kk = 0; kk < 2; ++kk) {
        if (EP == EP_QKV)
          acc[f][2] = __builtin_amdgcn_mfma_f32_16x16x32_bf16(af[f][kk], b2[kk], acc[f][2], 0, 0, 0);
        else
          acc[f][2] = __builtin_amdgcn_mfma_f32_16x16x32_bf16(b2[kk], af[f][kk], acc[f][2], 0, 0, 0);
      }
    __builtin_amdgcn_s_setprio(0);
    BAR();

    // ---- P4: read B n=3; stage A-hi(t+2); vmcnt once per K-tile ----
    bf16x8 b3[2];
    b3[0] = RDB(bc, 3, 0); b3[1] = RDB(bc, 3, 1);
    if (t + 2 < nt) STAGEH(1, t + 2, t & 1);
    BAR(); LGKM0();
    __builtin_amdgcn_s_setprio(1);
    #pragma unroll
    for (int f = 0; f < 8; ++f)
      #pragma unroll
      for (int kk = 0; kk < 2; ++kk) {
        if (EP == EP_QKV)
          acc[f][3] = __builtin_amdgcn_mfma_f32_16x16x32_bf16(af[f][kk], b3[kk], acc[f][3], 0, 0, 0);
        else
          acc[f][3] = __builtin_amdgcn_mfma_f32_16x16x32_bf16(b3[kk], af[f][kk], acc[f][3], 0, 0, 0);
      }
    __builtin_amdgcn_s_setprio(0);
    if (t + 2 < nt)      { WAIT_VM4(); }
    else if (t + 1 < nt) { WAIT_VM0(); }
    BAR();
  }

  // ----- epilogue -----
  if (EP == EP_QKV) {
    #pragma unroll
    for (int i = 0; i < 8; i++)
      #pragma unroll
      for (int j = 0; j < 4; j++) {
        int gm0 = m0 + wm * 128 + i * 16 + (l4 << 2);
        int gn  = n0 + wn * 64 + j * 16 + l15;
        int which = gn >> 10;
        int nn = gn & 1023, head = nn >> 6, d = nn & 63;
        int bb = gm0 >> 11, t = gm0 & 2047;
        float bv = bias[gn];
        if (which == 2) {
          int sbase = (t & ~31) + ((t >> 2) & 3) * 8 + ((t >> 4) & 1) * 4;
          f16x4 pk;
          #pragma unroll
          for (int jj = 0; jj < 4; jj++) pk[jj] = (f16)(acc[i][j][jj] + bv);
          *(f16x4*)((f16*)out_bf + (size_t)2 * NBH * SEQ * DK +
                    ((size_t)(bb * NH + head) * DK + d) * SEQ + sbase) = pk;
        } else {
          float scale = (which == 0) ? QSCALE : 1.0f;
          #pragma unroll
          for (int jj = 0; jj < 4; jj++) {
            float cv = (acc[i][j][jj] + bv) * scale;
            size_t idx = (size_t)which * (NBH * SEQ * DK) +
                         ((size_t)(bb * NH + head) * SEQ + (t + jj)) * DK + d;
            out_bf[idx] = (bf16)cv;
          }
        }
      }
  } else {  // EP_GELU, swapped C^T: lane holds C[gm][gn..gn+3]
    #pragma unroll
    for (int i = 0; i < 8; i++) {
      int gm = m0 + wm * 128 + i * 16 + l15;
      #pragma unroll
      for (int j = 0; j < 4; j++) {
        int gn = n0 + wn * 64 + j * 16 + (l4 << 2);
        float4 bv4 = *(const float4*)(bias + gn);
        bf16x4 pk;
        pk[0] = (bf16)gelu_fast(acc[i][j][0] + bv4.x);
        pk[1] = (bf16)gelu_fast(acc[i][j][1] + bv4.y);
        pk[2] = (bf16)gelu_fast(acc[i][j][2] + bv4.z);
        pk[3] = (bf16)gelu_fast(acc[i][j][3] + bv4.w);
        *(bf16x4*)(out_bf + (size_t)gm * N + gn) = pk;
      }
    }
  }
}

// ---------------- CFG1 GEMM (N=1024: O-proj, FFN2), RESID epilogue ---------
__global__ __launch_bounds__(512) void gemm_resid(
    const bf16* __restrict__ A, const bf16* __restrict__ W,
    const float* __restrict__ bias,
    const float* __restrict__ resid,
    float* __restrict__ out_f32,
    int M, int N, int K) {
  constexpr int BK = 64, RB = 128;
  constexpr int AB = 16384, TB = 49152, L = 6;
  __shared__ char lds[3 * TB];

  int tiles_n = N >> 8;
  int nwg = (M >> 7) * tiles_n;
  int bid = blockIdx.x;
  int swz = (bid & 7) * (nwg >> 3) + (bid >> 3);
  int bm = swz / tiles_n, bn = swz % tiles_n;
  int m0 = bm << 7, n0 = bn << 8;
  int tid = threadIdx.x, wid = tid >> 6, lane = tid & 63;
  int wm = wid >> 2, wn = wid & 3;
  int l15 = lane & 15, l4 = lane >> 4;

  f32x4 acc[4][4];
  #pragma unroll
  for (int i = 0; i < 4; i++)
    #pragma unroll
    for (int j = 0; j < 4; j++)
      #pragma unroll
      for (int e = 0; e < 4; e++) acc[i][j][e] = 0.f;

  auto STAGE = [&](int kt, int nb) {
    char* buf = lds + nb * TB;
    #pragma unroll
    for (int l = 0; l < L; ++l) {
      bool isA = l < 2;
      int o = (isA ? l : l - 2) * 8192 + tid * 16;
      int row = o >> 7;
      int g = (o >> 4) & 7;
      int gs = g ^ (row & 7);
      const bf16* src = (isA ? A + (size_t)(m0 + row) * K
                             : W + (size_t)(n0 + row) * K) + kt * BK + gs * 8;
      gload_lds16(src, buf + (isA ? 0 : AB) + o);
    }
  };

  int nt = K / BK;
  STAGE(0, 0);
  STAGE(1, 1);
  asm volatile("s_waitcnt vmcnt(6)" ::: "memory");
  __builtin_amdgcn_sched_barrier(0);
  BAR();

  for (int t = 0; t < nt; ++t) {
    int cb = t % 3, nb = cb >= 1 ? cb - 1 : 2;
    const char* bc = lds + cb * TB;
    if (t + 2 < nt) STAGE(t + 2, nb);

    bf16x8 af[4][2], bfr[4][2];
    #pragma unroll
    for (int f = 0; f < 4; ++f)
      #pragma unroll
      for (int kk = 0; kk < 2; ++kk) {
        int row = wm * 64 + f * 16 + l15;
        af[f][kk] = *(const bf16x8*)(bc + row * RB + (((kk << 2) + l4) ^ (row & 7)) * 16);
      }
    #pragma unroll
    for (int fc = 0; fc < 4; ++fc)
      #pragma unroll
      for (int kk = 0; kk < 2; ++kk) {
        int row = wn * 64 + fc * 16 + l15;
        bfr[fc][kk] = *(const bf16x8*)(bc + AB + row * RB + (((kk << 2) + l4) ^ (row & 7)) * 16);
      }

    __builtin_amdgcn_s_setprio(1);
    #pragma unroll
    for (int f = 0; f < 4; ++f)
      #pragma unroll
      for (int fc = 0; fc < 4; ++fc)
        #pragma unroll
        for (int kk = 0; kk < 2; ++kk)
          acc[f][fc] = __builtin_amdgcn_mfma_f32_16x16x32_bf16(bfr[fc][kk], af[f][kk],
                                                               acc[f][fc], 0, 0, 0);
    __builtin_amdgcn_s_setprio(0);

    if (t + 2 < nt) {
      asm volatile("s_waitcnt vmcnt(6)" ::: "memory");
      __builtin_amdgcn_sched_barrier(0);
    } else if (t + 1 < nt) {
      WAIT_VM0();
    }
    BAR();
  }

  #pragma unroll
  for (int i = 0; i < 4; i++) {
    int gm = m0 + wm * 64 + i * 16 + l15;
    #pragma unroll
    for (int j = 0; j < 4; j++) {
      int gn = n0 + wn * 64 + j * 16 + (l4 << 2);
      float4 bv4 = *(const float4*)(bias + gn);
      size_t idx = (size_t)gm * N + gn;
      float4 rv = *(const float4*)(resid + idx);
      float4 ov;
      ov.x = rv.x + acc[i][j][0] + bv4.x;
      ov.y = rv.y + acc[i][j][1] + bv4.y;
      ov.z = rv.z + acc[i][j][2] + bv4.z;
      ov.w = rv.w + acc[i][j][3] + bv4.w;
      *(float4*)(out_f32 + idx) = ov;
    }
  }
}

// ---------------- Flash attention (R16: 2 Q-frags/wave, 32 q-rows) ---------
__global__ __launch_bounds__(512) void attn_kernel(
    const bf16* __restrict__ q, const bf16* __restrict__ k,
    const f16* __restrict__ vt, bf16* __restrict__ o) {
  __shared__ bf16 kt_lds[2][64 * 64];
  __shared__ f16  vt_lds[2][64 * 64];
  int bid = blockIdx.x;
  int swzb = (bid & 7) * 64 + (bid >> 3);
  int bh = swzb >> 3;
  int qt = swzb & 7;
  int t0 = qt << 8;
  int tid = threadIdx.x, wid = tid >> 6, lane = tid & 63;
  int l15 = lane & 15, l4 = lane >> 4;

  int kb0 = l15 * 128 + ((l4 ^ (l15 & 7)) << 4);
  int kb1 = l15 * 128 + (((4 + l4) ^ (l15 & 7)) << 4);
  int vb32[2];
  #pragma unroll
  for (int n = 0; n < 2; n++)
    vb32[n] = l15 * 128 + (((n * 4 + l4) ^ (l15 & 7)) << 4);

  bf16x8 qf[2][2];
  #pragma unroll
  for (int qr = 0; qr < 2; qr++) {
    const bf16* qbase = q + ((size_t)bh * SEQ + t0 + wid * 32 + qr * 16 + l15) * DK;
    qf[qr][0] = *(const bf16x8*)(qbase + (l4 << 3));
    qf[qr][1] = *(const bf16x8*)(qbase + 32 + (l4 << 3));
  }

  f16x8 vones8;
  #pragma unroll
  for (int e = 0; e < 8; e++) vones8[e] = (f16)1.f;
  float m_run[2] = {-1e30f, -1e30f};
  f32x4 acc_o[2][4];
  f32x4 acc_l[2];
  #pragma unroll
  for (int qr = 0; qr < 2; qr++) {
    #pragma unroll
    for (int nd = 0; nd < 4; nd++)
      #pragma unroll
      for (int e = 0; e < 4; e++) acc_o[qr][nd][e] = 0.f;
    #pragma unroll
    for (int e = 0; e < 4; e++) acc_l[qr][e] = 0.f;
  }

  int oK = tid * 16;
  int rowk = oK >> 7, gk = (oK >> 4) & 7;
  const bf16* gKsrc = k + ((size_t)bh * SEQ + rowk) * DK + ((gk ^ (rowk & 7)) << 3);
  int dV = oK >> 7, gd = (oK >> 4) & 7;
  const f16* gVsrc = vt + ((size_t)bh * DK + dV) * SEQ + ((gd ^ (dV & 7)) << 3);

  auto stage = [&](int buf, int t) {
    int kv0 = t * 64;
    gload_lds16(gKsrc + (size_t)kv0 * DK, (char*)&kt_lds[buf][0] + tid * 16);
    gload_lds16(gVsrc + kv0, (char*)&vt_lds[buf][0] + tid * 16);
  };

  stage(0, 0);
  WAIT_VM0();
  BAR();

  for (int t = 0; t < SEQ / 64; ++t) {
    int cur = t & 1;
    if (t < SEQ / 64 - 1) stage(cur ^ 1, t + 1);
    const char* kbase = (const char*)&kt_lds[cur][0];
    const char* vbase = (const char*)&vt_lds[cur][0];

    f32x4 accs[2][4];
    #pragma unroll
    for (int qr = 0; qr < 2; qr++)
      #pragma unroll
      for (int n = 0; n < 4; n++)
        #pragma unroll
        for (int e = 0; e < 4; e++) accs[qr][n][e] = 0.f;
    __builtin_amdgcn_s_setprio(1);
    #pragma unroll
    for (int n = 0; n < 4; n++) {
      bf16x8 kf0 = *(const bf16x8*)(kbase + kb0 + n * 2048);
      bf16x8 kf1 = *(const bf16x8*)(kbase + kb1 + n * 2048);
      #pragma unroll
      for (int qr = 0; qr < 2; qr++) {
        accs[qr][n] = __builtin_amdgcn_mfma_f32_16x16x32_bf16(kf0, qf[qr][0], accs[qr][n], 0, 0, 0);
        accs[qr][n] = __builtin_amdgcn_mfma_f32_16x16x32_bf16(kf1, qf[qr][1], accs[qr][n], 0, 0, 0);
      }
    }
    __builtin_amdgcn_s_setprio(0);

    f16x8 pa32[2][2];
    #pragma unroll
    for (int qr = 0; qr < 2; qr++) {
      float mloc = -1e30f;
      #pragma unroll
      for (int n = 0; n < 4; n++) {
        float a0 = fmaxf(accs[qr][n][0], accs[qr][n][1]);
        float a1 = fmaxf(accs[qr][n][2], accs[qr][n][3]);
        mloc = fmaxf(mloc, fmaxf(a0, a1));
      }
      float mt = fmaxf(mloc, __shfl_xor(mloc, 16, 64));
      mt = fmaxf(mt, __shfl_xor(mt, 32, 64));
      if (__any(mt > m_run[qr] + 8.0f)) {
        float mn = fmaxf(m_run[qr], mt);
        float sc = __builtin_amdgcn_exp2f(m_run[qr] - mn);
        m_run[qr] = mn;
        float scr0 = __shfl(sc, l4 * 20 + 0, 64);
        float scr1 = __shfl(sc, l4 * 20 + 1, 64);
        float scr2 = __shfl(sc, l4 * 20 + 2, 64);
        float scr3 = __shfl(sc, l4 * 20 + 3, 64);
        #pragma unroll
        for (int nd = 0; nd < 4; nd++) {
          acc_o[qr][nd][0] *= scr0; acc_o[qr][nd][1] *= scr1;
          acc_o[qr][nd][2] *= scr2; acc_o[qr][nd][3] *= scr3;
        }
        acc_l[qr][0] *= scr0; acc_l[qr][1] *= scr1;
        acc_l[qr][2] *= scr2; acc_l[qr][3] *= scr3;
      }
      #pragma unroll
      for (int n = 0; n < 2; n++) {
        float e0 = __builtin_amdgcn_exp2f(accs[qr][2*n][0] - m_run[qr]);
        float e1 = __builtin_amdgcn_exp2f(accs[qr][2*n][1] - m_run[qr]);
        float e2 = __builtin_amdgcn_exp2f(accs[qr][2*n][2] - m_run[qr]);
        float e3 = __builtin_amdgcn_exp2f(accs[qr][2*n][3] - m_run[qr]);
        float e4 = __builtin_amdgcn_exp2f(accs[qr][2*n+1][0] - m_run[qr]);
        float e5 = __builtin_amdgcn_exp2f(accs[qr][2*n+1][1] - m_run[qr]);
        float e6 = __builtin_amdgcn_exp2f(accs[qr][2*n+1][2] - m_run[qr]);
        float e7 = __builtin_amdgcn_exp2f(accs[qr][2*n+1][3] - m_run[qr]);
        hf16x2 p01 = __builtin_amdgcn_cvt_pkrtz(e0, e1);
        hf16x2 p23 = __builtin_amdgcn_cvt_pkrtz(e2, e3);
        hf16x2 p45 = __builtin_amdgcn_cvt_pkrtz(e4, e5);
        hf16x2 p67 = __builtin_amdgcn_cvt_pkrtz(e6, e7);
        hf16x4 lo = __builtin_shufflevector(p01, p23, 0, 1, 2, 3);
        hf16x4 hi = __builtin_shufflevector(p45, p67, 0, 1, 2, 3);
        hf16x8 cmb = __builtin_shufflevector(lo, hi, 0, 1, 2, 3, 4, 5, 6, 7);
        pa32[qr][n] = __builtin_bit_cast(f16x8, cmb);
      }
    }

    __builtin_amdgcn_s_setprio(1);
    #pragma unroll
    for (int n = 0; n < 2; n++) {
      #pragma unroll
      for (int nd = 0; nd < 4; nd++) {
        f16x8 vf = *(const f16x8*)(vbase + vb32[n] + nd * 2048);
        #pragma unroll
        for (int qr = 0; qr < 2; qr++)
          acc_o[qr][nd] = __builtin_amdgcn_mfma_f32_16x16x32_f16(pa32[qr][n], vf, acc_o[qr][nd], 0, 0, 0);
      }
      #pragma unroll
      for (int qr = 0; qr < 2; qr++)
        acc_l[qr] = __builtin_amdgcn_mfma_f32_16x16x32_f16(pa32[qr][n], vones8, acc_l[qr], 0, 0, 0);
    }
    __builtin_amdgcn_s_setprio(0);

    if (t < SEQ / 64 - 1) { WAIT_VM0(); }
    BAR();
  }

  int bb = bh >> 4, hh = bh & 15;
  #pragma unroll
  for (int qr = 0; qr < 2; qr++) {
    float rl0 = 1.0f / acc_l[qr][0], rl1 = 1.0f / acc_l[qr][1];
    float rl2 = 1.0f / acc_l[qr][2], rl3 = 1.0f / acc_l[qr][3];
    int rowb = t0 + wid * 32 + qr * 16 + l4 * 4;
    #pragma unroll
    for (int nd = 0; nd < 4; nd++) {
      int d = nd * 16 + l15;
      o[((size_t)bb * SEQ + rowb + 0) * D_MODEL + hh * DK + d] = (bf16)(acc_o[qr][nd][0] * rl0);
      o[((size_t)bb * SEQ + rowb + 1) * D_MODEL + hh * DK + d] = (bf16)(acc_o[qr][nd][1] * rl1);
      o[((size_t)bb * SEQ + rowb + 2) * D_MODEL + hh * DK + d] = (bf16)(acc_o[qr][nd][2] * rl2);
      o[((size_t)bb * SEQ + rowb + 3) * D_MODEL + hh * DK + d] = (bf16)(acc_o[qr][nd][3] * rl3);
    }
  }
}

// ---------------- launch ----------------
extern "C" void kernel_launch(void* const* d_in, const int* in_sizes, int n_in,
                              void* d_out, int out_size, void* d_ws, size_t ws_size,
                              hipStream_t stream) {
  const float* x    = (const float*)d_in[0];
  const float* ln1g = (const float*)d_in[1];
  const float* ln1b = (const float*)d_in[2];
  const float* wq   = (const float*)d_in[3];
  const float* bq   = (const float*)d_in[4];
  const float* wk   = (const float*)d_in[5];
  const float* bk   = (const float*)d_in[6];
  const float* wv   = (const float*)d_in[7];
  const float* bv   = (const float*)d_in[8];
  const float* wo   = (const float*)d_in[9];
  const float* bo   = (const float*)d_in[10];
  const float* ln2g = (const float*)d_in[11];
  const float* ln2b = (const float*)d_in[12];
  const float* w1   = (const float*)d_in[13];
  const float* b1   = (const float*)d_in[14];
  const float* w2   = (const float*)d_in[15];
  const float* b2   = (const float*)d_in[16];
  float* out = (float*)d_out;

  char* ws = (char*)d_ws;
  bf16* wqkv_b = (bf16*)(ws);                          // 6MB
  bf16* wo_b   = (bf16*)(ws + ((size_t)6  << 20));     // 2MB
  bf16* w1_b   = (bf16*)(ws + ((size_t)8  << 20));     // 8MB
  bf16* w2_b   = (bf16*)(ws + ((size_t)16 << 20));     // 8MB
  bf16* h_b    = (bf16*)(ws + ((size_t)24 << 20));     // 16MB
  bf16* qkv_b  = (bf16*)(ws + ((size_t)40 << 20));     // 48MB q|k|vT(f16)
  bf16* o_b    = (bf16*)(ws + ((size_t)88 << 20));     // 16MB
  bf16* ffn1_b = (bf16*)(ws + ((size_t)40 << 20));     // 64MB (over dead q,k,v,o)
  float* bqkv  = (float*)(ws + ((size_t)104 << 20));   // 12KB

  cast_w<<<1024, 256, 0, stream>>>(wq, wqkv_b, 1 << 20);
  cast_w<<<1024, 256, 0, stream>>>(wk, wqkv_b + (1 << 20), 1 << 20);
  cast_w<<<1024, 256, 0, stream>>>(wv, wqkv_b + (2 << 20), 1 << 20);
  cast_w<<<1024, 256, 0, stream>>>(wo, wo_b, 1 << 20);
  cast_w<<<4096, 256, 0, stream>>>(w1, w1_b, 1 << 22);
  cast_w<<<4096, 256, 0, stream>>>(w2, w2_b, 1 << 22);
  (void)hipMemcpyAsync(bqkv,        bq, 4096, hipMemcpyDeviceToDevice, stream);
  (void)hipMemcpyAsync(bqkv + 1024, bk, 4096, hipMemcpyDeviceToDevice, stream);
  (void)hipMemcpyAsync(bqkv + 2048, bv, 4096, hipMemcpyDeviceToDevice, stream);

  ln_kernel<<<MTOK, 256, 0, stream>>>(x, ln1g, ln1b, h_b);
  gemm256<EP_QKV><<<384, 512, 0, stream>>>(h_b, wqkv_b, bqkv, qkv_b,
                                           MTOK, 3072, 1024);
  attn_kernel<<<512, 512, 0, stream>>>(qkv_b, qkv_b + (size_t)NBH * SEQ * DK,
                                       (const f16*)(qkv_b + (size_t)2 * NBH * SEQ * DK),
                                       o_b);
  gemm_resid<<<256, 512, 0, stream>>>(o_b, wo_b, bo, x, out, MTOK, 1024, 1024);
  ln_kernel<<<MTOK, 256, 0, stream>>>(out, ln2g, ln2b, h_b);
  gemm256<EP_GELU><<<512, 512, 0, stream>>>(h_b, w1_b, b1, ffn1_b,
                                            MTOK, 4096, 1024);
  gemm_resid<<<256, 512, 0, stream>>>(ffn1_b, w2_b, b2, out, out, MTOK, 1024, 4096);
}

// Round 20
// 382.061 us; speedup vs baseline: 1.0693x; 1.0282x over previous
//
#include <hip/hip_runtime.h>
#include <math.h>

// EncoderBlock: pre-LN attention + FFN, bf16 MFMA compute, fp32 residual spine.
// B=4 T=2048 D=1024 H=16 dk=64 DFF=4096
// R3: swapped QK^T -> lane-local P. R10: PV 16x16x32_f16, kv-permuted V^T.
// R13: fast-erf GELU. R16: attn 2 Q-frags/wave. R17: C^T epilogue.
// R18: QKV/FFN1 256^2 4-phase GEMM, vmcnt(4)/K-tile.
// R19: balanced quadrant phases (m201-faithful): P1 read A-lo+B-lo (12),
//      P2 B-hi (4), P3 A-hi (8), P4 B-lo again (4); operand reg-caching.
//      All casts + bias copies fused into ONE kernel.

#define D_MODEL 1024
#define D_FF    4096
#define NH      16
#define BATCH   4
#define SEQ     2048
#define DK      64
#define MTOK    (BATCH*SEQ)   // 8192
#define NBH     (BATCH*NH)    // 64

typedef __bf16 bf16;
typedef _Float16 f16;
typedef bf16  bf16x4 __attribute__((ext_vector_type(4)));
typedef bf16  bf16x8 __attribute__((ext_vector_type(8)));
typedef f16   f16x4  __attribute__((ext_vector_type(4)));
typedef f16   f16x8  __attribute__((ext_vector_type(8)));
typedef __fp16 hf16x2 __attribute__((ext_vector_type(2)));
typedef __fp16 hf16x4 __attribute__((ext_vector_type(4)));
typedef __fp16 hf16x8 __attribute__((ext_vector_type(8)));
typedef float f32x4  __attribute__((ext_vector_type(4)));

__device__ __forceinline__ void gload_lds16(const void* g, void* l) {
  __builtin_amdgcn_global_load_lds(
      (__attribute__((address_space(1))) void*)g,
      (__attribute__((address_space(3))) void*)l, 16, 0, 0);
}

#define BAR() __builtin_amdgcn_s_barrier()
#define LGKM0() do { asm volatile("s_waitcnt lgkmcnt(0)" ::: "memory"); \
  __builtin_amdgcn_sched_barrier(0); } while (0)
#define WAIT_VM0() do { asm volatile("s_waitcnt vmcnt(0)" ::: "memory"); \
  __builtin_amdgcn_sched_barrier(0); } while (0)
#define WAIT_VM4() do { asm volatile("s_waitcnt vmcnt(4)" ::: "memory"); \
  __builtin_amdgcn_sched_barrier(0); } while (0)

// Branch-free GELU (exact-erf quality): A&S 7.1.26, |erf err| <= 1.5e-7.
__device__ __forceinline__ float gelu_fast(float x) {
  float ax = fabsf(x) * 0.70710678118654752f;
  float t  = 1.0f / (1.0f + 0.3275911f * ax);
  float p  = t * (0.254829592f + t * (-0.284496736f + t * (1.421413741f +
             t * (-1.453152027f + t * 1.061405429f))));
  float e  = __builtin_amdgcn_exp2f(ax * ax * -1.4426950408889634f);
  float er = 1.0f - p * e;
  er = __builtin_copysignf(er, x);
  return 0.5f * x * (1.0f + er);
}

// ---------------- fused weight casts + bias copies (one launch) ------------
__global__ __launch_bounds__(256) void fused_cast(
    const float* __restrict__ wq, const float* __restrict__ wk,
    const float* __restrict__ wv, const float* __restrict__ wo,
    const float* __restrict__ w1, const float* __restrict__ w2,
    const float* __restrict__ bq, const float* __restrict__ bk,
    const float* __restrict__ bv,
    bf16* __restrict__ wqkv_b, bf16* __restrict__ wo_b,
    bf16* __restrict__ w1_b, bf16* __restrict__ w2_b,
    float* __restrict__ bqkv) {
  int b = blockIdx.x;
  if (b >= 12288) {                       // 3 bias blocks
    int which = b - 12288;
    const float* s = (which == 0) ? bq : (which == 1) ? bk : bv;
    int i = threadIdx.x * 4;
    *(float4*)(bqkv + which * 1024 + i) = *(const float4*)(s + i);
    return;
  }
  size_t i = ((size_t)b * 256 + threadIdx.x) * 4;   // element index, 12M total
  int seg = (int)(i >> 20);
  const float* src;
  bf16* dst;
  if (seg < 3) {        // wq|wk|wv -> wqkv_b (contiguous)
    src = (seg == 0 ? wq : seg == 1 ? wk : wv) + (i & 0xFFFFF);
    dst = wqkv_b + i;
  } else if (seg == 3) {
    src = wo + (i - (3u << 20));  dst = wo_b + (i - (3u << 20));
  } else if (seg < 8) {
    src = w1 + (i - (4u << 20));  dst = w1_b + (i - (4u << 20));
  } else {
    src = w2 + (i - (8u << 20));  dst = w2_b + (i - (8u << 20));
  }
  float4 v = *(const float4*)src;
  bf16x4 o;
  o[0] = (bf16)v.x; o[1] = (bf16)v.y; o[2] = (bf16)v.z; o[3] = (bf16)v.w;
  *(bf16x4*)dst = o;
}

// ---------------- LayerNorm (fp32 in, bf16 out) ----------------
__global__ __launch_bounds__(256) void ln_kernel(const float* __restrict__ x,
                                                 const float* __restrict__ g,
                                                 const float* __restrict__ b,
                                                 bf16* __restrict__ out) {
  int row = blockIdx.x;
  int tid = threadIdx.x;
  const float* xr = x + (size_t)row * D_MODEL;
  float4 v = *(const float4*)(xr + tid * 4);
  float s  = v.x + v.y + v.z + v.w;
  float sq = v.x*v.x + v.y*v.y + v.z*v.z + v.w*v.w;
  #pragma unroll
  for (int off = 1; off < 64; off <<= 1) {
    s  += __shfl_xor(s,  off, 64);
    sq += __shfl_xor(sq, off, 64);
  }
  __shared__ float ls[4], lq[4];
  int wid = tid >> 6, lane = tid & 63;
  if (lane == 0) { ls[wid] = s; lq[wid] = sq; }
  __syncthreads();
  s  = ls[0] + ls[1] + ls[2] + ls[3];
  sq = lq[0] + lq[1] + lq[2] + lq[3];
  float mu   = s * (1.0f / D_MODEL);
  float var  = sq * (1.0f / D_MODEL) - mu * mu;
  float rstd = rsqrtf(var + 1e-5f);
  float4 gv = *(const float4*)(g + tid * 4);
  float4 bv = *(const float4*)(b + tid * 4);
  bf16x4 o;
  o[0] = (bf16)((v.x - mu) * rstd * gv.x + bv.x);
  o[1] = (bf16)((v.y - mu) * rstd * gv.y + bv.y);
  o[2] = (bf16)((v.z - mu) * rstd * gv.z + bv.z);
  o[3] = (bf16)((v.w - mu) * rstd * gv.w + bv.w);
  *(bf16x4*)(out + (size_t)row * D_MODEL + tid * 4) = o;
}

enum { EP_QKV = 0, EP_RESID = 1, EP_GELU = 2 };
#define QSCALE 0.18033688011112042f  // (1/8) * log2(e)

// ---------- 8-phase 256x256 GEMM (m201 port, balanced quadrants) -----------
// LDS/buffer 64KB: A rows 0-255 @0, B rows 0-255 @32768; g ^= row&7 swizzle.
// Half-tiles h: 0=A-lo 1=A-hi 2=B-lo 3=B-hi. Quadrant walk per K-tile:
// P1 (M0,N0): read A f0-3 (8) + B j0-1 (4);  stage B-lo(t+1)
// P2 (M0,N1): read B j2-3 (4)  [A cached];   stage B-hi(t+1)
// P3 (M1,N1): read A f4-7 (8)  [B cached];   stage A-lo(t+2)
// P4 (M1,N0): read B j0-1 (4)  [A cached];   stage A-hi(t+2); vmcnt(4)
template <int EP>
__global__ __launch_bounds__(512, 2) void gemm256(
    const bf16* __restrict__ A, const bf16* __restrict__ W,
    const float* __restrict__ bias,
    bf16* __restrict__ out_bf,
    int M, int N, int K) {
  __shared__ char lds[131072];
  int tiles_n = N >> 8;
  int nwg = (M >> 8) * tiles_n;
  int bid = blockIdx.x;
  int swz = (bid & 7) * (nwg >> 3) + (bid >> 3);
  int bm = swz / tiles_n, bn = swz % tiles_n;
  int m0 = bm << 8, n0 = bn << 8;
  int tid = threadIdx.x, wid = tid >> 6, lane = tid & 63;
  int wm = wid >> 2, wn = wid & 3;        // 2M x 4N, wave tile 128x64
  int l15 = lane & 15, l4 = lane >> 4;

  f32x4 acc[8][4];
  #pragma unroll
  for (int f = 0; f < 8; f++)
    #pragma unroll
    for (int n = 0; n < 4; n++)
      #pragma unroll
      for (int e = 0; e < 4; e++) acc[f][n][e] = 0.f;

  auto STAGEH = [&](int h, int kt, int bsel) {
    char* buf = lds + bsel * 65536;
    #pragma unroll
    for (int l = 0; l < 2; ++l) {
      int o = h * 16384 + l * 8192 + tid * 16;
      int row = (o >> 7) & 255;
      int g = (o >> 4) & 7;
      int gs = g ^ (row & 7);
      const bf16* src = (h < 2 ? A + (size_t)(m0 + row) * K
                               : W + (size_t)(n0 + row) * K) + kt * 64 + gs * 8;
      gload_lds16(src, buf + o);
    }
  };
  auto RDA = [&](const char* bc, int f, int kk) -> bf16x8 {
    int row = wm * 128 + f * 16 + l15;
    return *(const bf16x8*)(bc + row * 128 + (((kk << 2) + l4) ^ (row & 7)) * 16);
  };
  auto RDB = [&](const char* bc, int n, int kk) -> bf16x8 {
    int row = wn * 64 + n * 16 + l15;
    return *(const bf16x8*)(bc + 32768 + row * 128 + (((kk << 2) + l4) ^ (row & 7)) * 16);
  };
  auto MM = [&](f32x4& a, bf16x8 av, bf16x8 bv) {
    if (EP == EP_QKV) a = __builtin_amdgcn_mfma_f32_16x16x32_bf16(av, bv, a, 0, 0, 0);
    else              a = __builtin_amdgcn_mfma_f32_16x16x32_bf16(bv, av, a, 0, 0, 0);
  };

  int nt = K >> 6;
  STAGEH(0, 0, 0); STAGEH(1, 0, 0); STAGEH(2, 0, 0); STAGEH(3, 0, 0);
  STAGEH(0, 1, 1); STAGEH(1, 1, 1);
  WAIT_VM4();
  BAR();

  bf16x8 af[4][2], bq[2][2];
  for (int t = 0; t < nt; ++t) {
    const char* bc = lds + (t & 1) * 65536;

    // ---- P1 (M0,N0): read A f0-3 + B j0-1; stage B-lo(t+1) ----
    #pragma unroll
    for (int f = 0; f < 4; ++f) { af[f][0] = RDA(bc, f, 0); af[f][1] = RDA(bc, f, 1); }
    #pragma unroll
    for (int j = 0; j < 2; ++j) { bq[j][0] = RDB(bc, j, 0); bq[j][1] = RDB(bc, j, 1); }
    if (t + 1 < nt) STAGEH(2, t + 1, (t + 1) & 1);
    BAR(); LGKM0();
    __builtin_amdgcn_s_setprio(1);
    #pragma unroll
    for (int f = 0; f < 4; ++f)
      #pragma unroll
      for (int j = 0; j < 2; ++j)
        #pragma unroll
        for (int kk = 0; kk < 2; ++kk) MM(acc[f][j], af[f][kk], bq[j][kk]);
    __builtin_amdgcn_s_setprio(0);
    BAR();

    // ---- P2 (M0,N1): read B j2-3; stage B-hi(t+1) ----
    #pragma unroll
    for (int j = 0; j < 2; ++j) { bq[j][0] = RDB(bc, 2 + j, 0); bq[j][1] = RDB(bc, 2 + j, 1); }
    if (t + 1 < nt) STAGEH(3, t + 1, (t + 1) & 1);
    BAR(); LGKM0();
    __builtin_amdgcn_s_setprio(1);
    #pragma unroll
    for (int f = 0; f < 4; ++f)
      #pragma unroll
      for (int j = 0; j < 2; ++j)
        #pragma unroll
        for (int kk = 0; kk < 2; ++kk) MM(acc[f][2 + j], af[f][kk], bq[j][kk]);
    __builtin_amdgcn_s_setprio(0);
    BAR();

    // ---- P3 (M1,N1): read A f4-7; stage A-lo(t+2) ----
    #pragma unroll
    for (int f = 0; f < 4; ++f) { af[f][0] = RDA(bc, 4 + f, 0); af[f][1] = RDA(bc, 4 + f, 1); }
    if (t + 2 < nt) STAGEH(0, t + 2, t & 1);
    BAR(); LGKM0();
    __builtin_amdgcn_s_setprio(1);
    #pragma unroll
    for (int f = 0; f < 4; ++f)
      #pragma unroll
      for (int j = 0; j < 2; ++j)
        #pragma unroll
        for (int kk = 0; kk < 2; ++kk) MM(acc[4 + f][2 + j], af[f][kk], bq[j][kk]);
    __builtin_amdgcn_s_setprio(0);
    BAR();

    // ---- P4 (M1,N0): read B j0-1; stage A-hi(t+2); vmcnt once ----
    #pragma unroll
    for (int j = 0; j < 2; ++j) { bq[j][0] = RDB(bc, j, 0); bq[j][1] = RDB(bc, j, 1); }
    if (t + 2 < nt) STAGEH(1, t + 2, t & 1);
    BAR(); LGKM0();
    __builtin_amdgcn_s_setprio(1);
    #pragma unroll
    for (int f = 0; f < 4; ++f)
      #pragma unroll
      for (int j = 0; j < 2; ++j)
        #pragma unroll
        for (int kk = 0; kk < 2; ++kk) MM(acc[4 + f][j], af[f][kk], bq[j][kk]);
    __builtin_amdgcn_s_setprio(0);
    if (t + 2 < nt)      { WAIT_VM4(); }
    else if (t + 1 < nt) { WAIT_VM0(); }
    BAR();
  }

  // ----- epilogue -----
  if (EP == EP_QKV) {
    #pragma unroll
    for (int i = 0; i < 8; i++)
      #pragma unroll
      for (int j = 0; j < 4; j++) {
        int gm0 = m0 + wm * 128 + i * 16 + (l4 << 2);
        int gn  = n0 + wn * 64 + j * 16 + l15;
        int which = gn >> 10;
        int nn = gn & 1023, head = nn >> 6, d = nn & 63;
        int bb = gm0 >> 11, t = gm0 & 2047;
        float bv = bias[gn];
        if (which == 2) {
          int sbase = (t & ~31) + ((t >> 2) & 3) * 8 + ((t >> 4) & 1) * 4;
          f16x4 pk;
          #pragma unroll
          for (int jj = 0; jj < 4; jj++) pk[jj] = (f16)(acc[i][j][jj] + bv);
          *(f16x4*)((f16*)out_bf + (size_t)2 * NBH * SEQ * DK +
                    ((size_t)(bb * NH + head) * DK + d) * SEQ + sbase) = pk;
        } else {
          float scale = (which == 0) ? QSCALE : 1.0f;
          #pragma unroll
          for (int jj = 0; jj < 4; jj++) {
            float cv = (acc[i][j][jj] + bv) * scale;
            size_t idx = (size_t)which * (NBH * SEQ * DK) +
                         ((size_t)(bb * NH + head) * SEQ + (t + jj)) * DK + d;
            out_bf[idx] = (bf16)cv;
          }
        }
      }
  } else {  // EP_GELU, C^T: lane holds C[gm][gn..gn+3]
    #pragma unroll
    for (int i = 0; i < 8; i++) {
      int gm = m0 + wm * 128 + i * 16 + l15;
      #pragma unroll
      for (int j = 0; j < 4; j++) {
        int gn = n0 + wn * 64 + j * 16 + (l4 << 2);
        float4 bv4 = *(const float4*)(bias + gn);
        bf16x4 pk;
        pk[0] = (bf16)gelu_fast(acc[i][j][0] + bv4.x);
        pk[1] = (bf16)gelu_fast(acc[i][j][1] + bv4.y);
        pk[2] = (bf16)gelu_fast(acc[i][j][2] + bv4.z);
        pk[3] = (bf16)gelu_fast(acc[i][j][3] + bv4.w);
        *(bf16x4*)(out_bf + (size_t)gm * N + gn) = pk;
      }
    }
  }
}

// ---------------- CFG1 GEMM (N=1024: O-proj, FFN2), RESID epilogue ---------
__global__ __launch_bounds__(512) void gemm_resid(
    const bf16* __restrict__ A, const bf16* __restrict__ W,
    const float* __restrict__ bias,
    const float* __restrict__ resid,
    float* __restrict__ out_f32,
    int M, int N, int K) {
  constexpr int BK = 64, RB = 128;
  constexpr int AB = 16384, TB = 49152, L = 6;
  __shared__ char lds[3 * TB];

  int tiles_n = N >> 8;
  int nwg = (M >> 7) * tiles_n;
  int bid = blockIdx.x;
  int swz = (bid & 7) * (nwg >> 3) + (bid >> 3);
  int bm = swz / tiles_n, bn = swz % tiles_n;
  int m0 = bm << 7, n0 = bn << 8;
  int tid = threadIdx.x, wid = tid >> 6, lane = tid & 63;
  int wm = wid >> 2, wn = wid & 3;
  int l15 = lane & 15, l4 = lane >> 4;

  f32x4 acc[4][4];
  #pragma unroll
  for (int i = 0; i < 4; i++)
    #pragma unroll
    for (int j = 0; j < 4; j++)
      #pragma unroll
      for (int e = 0; e < 4; e++) acc[i][j][e] = 0.f;

  auto STAGE = [&](int kt, int nb) {
    char* buf = lds + nb * TB;
    #pragma unroll
    for (int l = 0; l < L; ++l) {
      bool isA = l < 2;
      int o = (isA ? l : l - 2) * 8192 + tid * 16;
      int row = o >> 7;
      int g = (o >> 4) & 7;
      int gs = g ^ (row & 7);
      const bf16* src = (isA ? A + (size_t)(m0 + row) * K
                             : W + (size_t)(n0 + row) * K) + kt * BK + gs * 8;
      gload_lds16(src, buf + (isA ? 0 : AB) + o);
    }
  };

  int nt = K / BK;
  STAGE(0, 0);
  STAGE(1, 1);
  asm volatile("s_waitcnt vmcnt(6)" ::: "memory");
  __builtin_amdgcn_sched_barrier(0);
  BAR();

  for (int t = 0; t < nt; ++t) {
    int cb = t % 3, nb = cb >= 1 ? cb - 1 : 2;
    const char* bc = lds + cb * TB;
    if (t + 2 < nt) STAGE(t + 2, nb);

    bf16x8 af[4][2], bfr[4][2];
    #pragma unroll
    for (int f = 0; f < 4; ++f)
      #pragma unroll
      for (int kk = 0; kk < 2; ++kk) {
        int row = wm * 64 + f * 16 + l15;
        af[f][kk] = *(const bf16x8*)(bc + row * RB + (((kk << 2) + l4) ^ (row & 7)) * 16);
      }
    #pragma unroll
    for (int fc = 0; fc < 4; ++fc)
      #pragma unroll
      for (int kk = 0; kk < 2; ++kk) {
        int row = wn * 64 + fc * 16 + l15;
        bfr[fc][kk] = *(const bf16x8*)(bc + AB + row * RB + (((kk << 2) + l4) ^ (row & 7)) * 16);
      }

    __builtin_amdgcn_s_setprio(1);
    #pragma unroll
    for (int f = 0; f < 4; ++f)
      #pragma unroll
      for (int fc = 0; fc < 4; ++fc)
        #pragma unroll
        for (int kk = 0; kk < 2; ++kk)
          acc[f][fc] = __builtin_amdgcn_mfma_f32_16x16x32_bf16(bfr[fc][kk], af[f][kk],
                                                               acc[f][fc], 0, 0, 0);
    __builtin_amdgcn_s_setprio(0);

    if (t + 2 < nt) {
      asm volatile("s_waitcnt vmcnt(6)" ::: "memory");
      __builtin_amdgcn_sched_barrier(0);
    } else if (t + 1 < nt) {
      WAIT_VM0();
    }
    BAR();
  }

  #pragma unroll
  for (int i = 0; i < 4; i++) {
    int gm = m0 + wm * 64 + i * 16 + l15;
    #pragma unroll
    for (int j = 0; j < 4; j++) {
      int gn = n0 + wn * 64 + j * 16 + (l4 << 2);
      float4 bv4 = *(const float4*)(bias + gn);
      size_t idx = (size_t)gm * N + gn;
      float4 rv = *(const float4*)(resid + idx);
      float4 ov;
      ov.x = rv.x + acc[i][j][0] + bv4.x;
      ov.y = rv.y + acc[i][j][1] + bv4.y;
      ov.z = rv.z + acc[i][j][2] + bv4.z;
      ov.w = rv.w + acc[i][j][3] + bv4.w;
      *(float4*)(out_f32 + idx) = ov;
    }
  }
}

// ---------------- Flash attention (R16: 2 Q-frags/wave, 32 q-rows) ---------
__global__ __launch_bounds__(512) void attn_kernel(
    const bf16* __restrict__ q, const bf16* __restrict__ k,
    const f16* __restrict__ vt, bf16* __restrict__ o) {
  __shared__ bf16 kt_lds[2][64 * 64];
  __shared__ f16  vt_lds[2][64 * 64];
  int bid = blockIdx.x;
  int swzb = (bid & 7) * 64 + (bid >> 3);
  int bh = swzb >> 3;
  int qt = swzb & 7;
  int t0 = qt << 8;
  int tid = threadIdx.x, wid = tid >> 6, lane = tid & 63;
  int l15 = lane & 15, l4 = lane >> 4;

  int kb0 = l15 * 128 + ((l4 ^ (l15 & 7)) << 4);
  int kb1 = l15 * 128 + (((4 + l4) ^ (l15 & 7)) << 4);
  int vb32[2];
  #pragma unroll
  for (int n = 0; n < 2; n++)
    vb32[n] = l15 * 128 + (((n * 4 + l4) ^ (l15 & 7)) << 4);

  bf16x8 qf[2][2];
  #pragma unroll
  for (int qr = 0; qr < 2; qr++) {
    const bf16* qbase = q + ((size_t)bh * SEQ + t0 + wid * 32 + qr * 16 + l15) * DK;
    qf[qr][0] = *(const bf16x8*)(qbase + (l4 << 3));
    qf[qr][1] = *(const bf16x8*)(qbase + 32 + (l4 << 3));
  }

  f16x8 vones8;
  #pragma unroll
  for (int e = 0; e < 8; e++) vones8[e] = (f16)1.f;
  float m_run[2] = {-1e30f, -1e30f};
  f32x4 acc_o[2][4];
  f32x4 acc_l[2];
  #pragma unroll
  for (int qr = 0; qr < 2; qr++) {
    #pragma unroll
    for (int nd = 0; nd < 4; nd++)
      #pragma unroll
      for (int e = 0; e < 4; e++) acc_o[qr][nd][e] = 0.f;
    #pragma unroll
    for (int e = 0; e < 4; e++) acc_l[qr][e] = 0.f;
  }

  int oK = tid * 16;
  int rowk = oK >> 7, gk = (oK >> 4) & 7;
  const bf16* gKsrc = k + ((size_t)bh * SEQ + rowk) * DK + ((gk ^ (rowk & 7)) << 3);
  int dV = oK >> 7, gd = (oK >> 4) & 7;
  const f16* gVsrc = vt + ((size_t)bh * DK + dV) * SEQ + ((gd ^ (dV & 7)) << 3);

  auto stage = [&](int buf, int t) {
    int kv0 = t * 64;
    gload_lds16(gKsrc + (size_t)kv0 * DK, (char*)&kt_lds[buf][0] + tid * 16);
    gload_lds16(gVsrc + kv0, (char*)&vt_lds[buf][0] + tid * 16);
  };

  stage(0, 0);
  WAIT_VM0();
  BAR();

  for (int t = 0; t < SEQ / 64; ++t) {
    int cur = t & 1;
    if (t < SEQ / 64 - 1) stage(cur ^ 1, t + 1);
    const char* kbase = (const char*)&kt_lds[cur][0];
    const char* vbase = (const char*)&vt_lds[cur][0];

    f32x4 accs[2][4];
    #pragma unroll
    for (int qr = 0; qr < 2; qr++)
      #pragma unroll
      for (int n = 0; n < 4; n++)
        #pragma unroll
        for (int e = 0; e < 4; e++) accs[qr][n][e] = 0.f;
    __builtin_amdgcn_s_setprio(1);
    #pragma unroll
    for (int n = 0; n < 4; n++) {
      bf16x8 kf0 = *(const bf16x8*)(kbase + kb0 + n * 2048);
      bf16x8 kf1 = *(const bf16x8*)(kbase + kb1 + n * 2048);
      #pragma unroll
      for (int qr = 0; qr < 2; qr++) {
        accs[qr][n] = __builtin_amdgcn_mfma_f32_16x16x32_bf16(kf0, qf[qr][0], accs[qr][n], 0, 0, 0);
        accs[qr][n] = __builtin_amdgcn_mfma_f32_16x16x32_bf16(kf1, qf[qr][1], accs[qr][n], 0, 0, 0);
      }
    }
    __builtin_amdgcn_s_setprio(0);

    f16x8 pa32[2][2];
    #pragma unroll
    for (int qr = 0; qr < 2; qr++) {
      float mloc = -1e30f;
      #pragma unroll
      for (int n = 0; n < 4; n++) {
        float a0 = fmaxf(accs[qr][n][0], accs[qr][n][1]);
        float a1 = fmaxf(accs[qr][n][2], accs[qr][n][3]);
        mloc = fmaxf(mloc, fmaxf(a0, a1));
      }
      float mt = fmaxf(mloc, __shfl_xor(mloc, 16, 64));
      mt = fmaxf(mt, __shfl_xor(mt, 32, 64));
      if (__any(mt > m_run[qr] + 8.0f)) {
        float mn = fmaxf(m_run[qr], mt);
        float sc = __builtin_amdgcn_exp2f(m_run[qr] - mn);
        m_run[qr] = mn;
        float scr0 = __shfl(sc, l4 * 20 + 0, 64);
        float scr1 = __shfl(sc, l4 * 20 + 1, 64);
        float scr2 = __shfl(sc, l4 * 20 + 2, 64);
        float scr3 = __shfl(sc, l4 * 20 + 3, 64);
        #pragma unroll
        for (int nd = 0; nd < 4; nd++) {
          acc_o[qr][nd][0] *= scr0; acc_o[qr][nd][1] *= scr1;
          acc_o[qr][nd][2] *= scr2; acc_o[qr][nd][3] *= scr3;
        }
        acc_l[qr][0] *= scr0; acc_l[qr][1] *= scr1;
        acc_l[qr][2] *= scr2; acc_l[qr][3] *= scr3;
      }
      #pragma unroll
      for (int n = 0; n < 2; n++) {
        float e0 = __builtin_amdgcn_exp2f(accs[qr][2*n][0] - m_run[qr]);
        float e1 = __builtin_amdgcn_exp2f(accs[qr][2*n][1] - m_run[qr]);
        float e2 = __builtin_amdgcn_exp2f(accs[qr][2*n][2] - m_run[qr]);
        float e3 = __builtin_amdgcn_exp2f(accs[qr][2*n][3] - m_run[qr]);
        float e4 = __builtin_amdgcn_exp2f(accs[qr][2*n+1][0] - m_run[qr]);
        float e5 = __builtin_amdgcn_exp2f(accs[qr][2*n+1][1] - m_run[qr]);
        float e6 = __builtin_amdgcn_exp2f(accs[qr][2*n+1][2] - m_run[qr]);
        float e7 = __builtin_amdgcn_exp2f(accs[qr][2*n+1][3] - m_run[qr]);
        hf16x2 p01 = __builtin_amdgcn_cvt_pkrtz(e0, e1);
        hf16x2 p23 = __builtin_amdgcn_cvt_pkrtz(e2, e3);
        hf16x2 p45 = __builtin_amdgcn_cvt_pkrtz(e4, e5);
        hf16x2 p67 = __builtin_amdgcn_cvt_pkrtz(e6, e7);
        hf16x4 lo = __builtin_shufflevector(p01, p23, 0, 1, 2, 3);
        hf16x4 hi = __builtin_shufflevector(p45, p67, 0, 1, 2, 3);
        hf16x8 cmb = __builtin_shufflevector(lo, hi, 0, 1, 2, 3, 4, 5, 6, 7);
        pa32[qr][n] = __builtin_bit_cast(f16x8, cmb);
      }
    }

    __builtin_amdgcn_s_setprio(1);
    #pragma unroll
    for (int n = 0; n < 2; n++) {
      #pragma unroll
      for (int nd = 0; nd < 4; nd++) {
        f16x8 vf = *(const f16x8*)(vbase + vb32[n] + nd * 2048);
        #pragma unroll
        for (int qr = 0; qr < 2; qr++)
          acc_o[qr][nd] = __builtin_amdgcn_mfma_f32_16x16x32_f16(pa32[qr][n], vf, acc_o[qr][nd], 0, 0, 0);
      }
      #pragma unroll
      for (int qr = 0; qr < 2; qr++)
        acc_l[qr] = __builtin_amdgcn_mfma_f32_16x16x32_f16(pa32[qr][n], vones8, acc_l[qr], 0, 0, 0);
    }
    __builtin_amdgcn_s_setprio(0);

    if (t < SEQ / 64 - 1) { WAIT_VM0(); }
    BAR();
  }

  int bb = bh >> 4, hh = bh & 15;
  #pragma unroll
  for (int qr = 0; qr < 2; qr++) {
    float rl0 = 1.0f / acc_l[qr][0], rl1 = 1.0f / acc_l[qr][1];
    float rl2 = 1.0f / acc_l[qr][2], rl3 = 1.0f / acc_l[qr][3];
    int rowb = t0 + wid * 32 + qr * 16 + l4 * 4;
    #pragma unroll
    for (int nd = 0; nd < 4; nd++) {
      int d = nd * 16 + l15;
      o[((size_t)bb * SEQ + rowb + 0) * D_MODEL + hh * DK + d] = (bf16)(acc_o[qr][nd][0] * rl0);
      o[((size_t)bb * SEQ + rowb + 1) * D_MODEL + hh * DK + d] = (bf16)(acc_o[qr][nd][1] * rl1);
      o[((size_t)bb * SEQ + rowb + 2) * D_MODEL + hh * DK + d] = (bf16)(acc_o[qr][nd][2] * rl2);
      o[((size_t)bb * SEQ + rowb + 3) * D_MODEL + hh * DK + d] = (bf16)(acc_o[qr][nd][3] * rl3);
    }
  }
}

// ---------------- launch ----------------
extern "C" void kernel_launch(void* const* d_in, const int* in_sizes, int n_in,
                              void* d_out, int out_size, void* d_ws, size_t ws_size,
                              hipStream_t stream) {
  const float* x    = (const float*)d_in[0];
  const float* ln1g = (const float*)d_in[1];
  const float* ln1b = (const float*)d_in[2];
  const float* wq   = (const float*)d_in[3];
  const float* bq   = (const float*)d_in[4];
  const float* wk   = (const float*)d_in[5];
  const float* bk   = (const float*)d_in[6];
  const float* wv   = (const float*)d_in[7];
  const float* bv   = (const float*)d_in[8];
  const float* wo   = (const float*)d_in[9];
  const float* bo   = (const float*)d_in[10];
  const float* ln2g = (const float*)d_in[11];
  const float* ln2b = (const float*)d_in[12];
  const float* w1   = (const float*)d_in[13];
  const float* b1   = (const float*)d_in[14];
  const float* w2   = (const float*)d_in[15];
  const float* b2   = (const float*)d_in[16];
  float* out = (float*)d_out;

  char* ws = (char*)d_ws;
  bf16* wqkv_b = (bf16*)(ws);                          // 6MB
  bf16* wo_b   = (bf16*)(ws + ((size_t)6  << 20));     // 2MB
  bf16* w1_b   = (bf16*)(ws + ((size_t)8  << 20));     // 8MB
  bf16* w2_b   = (bf16*)(ws + ((size_t)16 << 20));     // 8MB
  bf16* h_b    = (bf16*)(ws + ((size_t)24 << 20));     // 16MB
  bf16* qkv_b  = (bf16*)(ws + ((size_t)40 << 20));     // 48MB q|k|vT(f16)
  bf16* o_b    = (bf16*)(ws + ((size_t)88 << 20));     // 16MB
  bf16* ffn1_b = (bf16*)(ws + ((size_t)40 << 20));     // 64MB (over dead q,k,v,o)
  float* bqkv  = (float*)(ws + ((size_t)104 << 20));   // 12KB

  fused_cast<<<12291, 256, 0, stream>>>(wq, wk, wv, wo, w1, w2, bq, bk, bv,
                                        wqkv_b, wo_b, w1_b, w2_b, bqkv);
  ln_kernel<<<MTOK, 256, 0, stream>>>(x, ln1g, ln1b, h_b);
  gemm256<EP_QKV><<<384, 512, 0, stream>>>(h_b, wqkv_b, bqkv, qkv_b,
                                           MTOK, 3072, 1024);
  attn_kernel<<<512, 512, 0, stream>>>(qkv_b, qkv_b + (size_t)NBH * SEQ * DK,
                                       (const f16*)(qkv_b + (size_t)2 * NBH * SEQ * DK),
                                       o_b);
  gemm_resid<<<256, 512, 0, stream>>>(o_b, wo_b, bo, x, out, MTOK, 1024, 1024);
  ln_kernel<<<MTOK, 256, 0, stream>>>(out, ln2g, ln2b, h_b);
  gemm256<EP_GELU><<<512, 512, 0, stream>>>(h_b, w1_b, b1, ffn1_b,
                                            MTOK, 4096, 1024);
  gemm_resid<<<256, 512, 0, stream>>>(ffn1_b, w2_b, b2, out, out, MTOK, 1024, 4096);
}